// Round 1
// 100.716 us; speedup vs baseline: 1.0991x; 1.0991x over previous
//
#include <hip/hip_runtime.h>
#include <math.h>

// ---------------------------------------------------------------------------
// Problem: B=32, L=1024, C=34, PATCH=16, d=256, E=8, pred=96.
// Algebraic reductions (verified R1-R7):
//   * final [:, :, :1] slice -> only channel n=0 per batch (series x[b,:,2])
//   * flat[:, :1024] truncation -> only patches p=0..3 contribute
// => 32 series, 4 patches each, 8 expert 256x256 matvecs per (b,p), one
//    96x1024 head matvec per b.  ~0.3 GFLOP; latency/occupancy-bound.
//
// LESSONS: R4 - no intra-kernel cross-workgroup handoff (XCD L2 non-coherent).
//   R5 - redundant recompute + uncoalesced rows >> launch cost.
//   R6 - 2-batch Wt tiling at 2 blocks/CU beat 4-batch at 1 block/CU (R7):
//        occupancy > traffic in this regime.
//
// R9: push occupancy further (counters: no kernel >40us; all traffic L2-
//   resident; FMA floor ~3.4us => latency-bound at 2 waves/SIMD):
//   k_expert: split d-reduction in half -> 1024 blocks (4 blocks/CU,
//             4 waves/SIMD), 16 disjoint partial buffers (e, d-half).
//   k_head  : split pred across 8 kq groups -> 256 blocks (full chip).
//   k_stats : unchanged (transpose runs concurrent with stats path).
// ---------------------------------------------------------------------------

#define NB 32
#define LSEQ 1024
#define CCH 34
#define NP 4
#define DMODEL 256
#define NEXP 8
#define PRED 96
#define NPART (2 * NEXP)                        // 16 partial buffers (e, dh)

#define WT_FLOATS    (NEXP * DMODEL * DMODEL)   // 524288
#define XP_FLOATS    (NB * NP * DMODEL)         // 32768
#define GATES_FLOATS (NB * NP * NEXP)           // 1024
#define STATS_FLOATS (NB * 2)                   // 64

// ---------------------------------------------------------------------------
// Kernel A: distributed transpose + (blocks 0-31) stats path.
// grid = 256, block = 256.  LDS tile [64][33] -> conflict-free both ways.
// ---------------------------------------------------------------------------
__global__ __launch_bounds__(256) void k_stats(
    const float* __restrict__ x,
    const float* __restrict__ W_proj, const float* __restrict__ b_proj,
    const float* __restrict__ W_router, const float* __restrict__ b_router,
    const float* __restrict__ W_experts, float* __restrict__ Wt,
    float* __restrict__ xp_ws, float* __restrict__ gates_ws,
    float* __restrict__ stats_ws)
{
    const int bid = blockIdx.x;
    const int tid = threadIdx.x;
    const int b = bid;            // batch id, valid only for bid < NB

    __shared__ float tile[64][33];
    __shared__ float xn[LSEQ];
    __shared__ float xp_s[NP * DMODEL];
    __shared__ float red[8];
    __shared__ float lg[32];
    __shared__ float mean_s, rstd_s;

    // stats blocks: issue the strided series loads FIRST (long HBM latency)
    float v[4];
    if (b < NB) {
        #pragma unroll
        for (int i = 0; i < 4; ++i)
            v[i] = x[(size_t)(b * LSEQ + tid + 256 * i) * CCH + 2];
    }

    // ---- distributed transpose: one 64(h) x 32(d) tile per block
    {
        const int e  = bid >> 5;
        const int h0 = ((bid >> 3) & 3) << 6;
        const int d0 = (bid & 7) << 5;
        const float* src = W_experts + ((size_t)e << 16);
        float*       dst = Wt        + ((size_t)e << 16);
        const int dx = tid & 31, hy = tid >> 5;   // load: 32 d-lanes x 8 h-rows
        const int hx = tid & 63, dy = tid >> 6;   // store: 64 h-lanes x 4 d-rows
        #pragma unroll
        for (int i = 0; i < 8; ++i) {
            const int hh = hy + 8 * i;
            tile[hh][dx] = src[(size_t)(h0 + hh) * DMODEL + d0 + dx];
        }
        __syncthreads();
        #pragma unroll
        for (int i = 0; i < 8; ++i) {
            const int dd = dy + 4 * i;
            dst[(size_t)(d0 + dd) * DMODEL + h0 + hx] = tile[hx][dd];
        }
    }

    if (b >= NB) return;   // transpose-only blocks done

    // ---- stats over the 1024-length series
    float s = 0.f, sq = 0.f;
    #pragma unroll
    for (int i = 0; i < 4; ++i) { s += v[i]; sq += v[i] * v[i]; }
    #pragma unroll
    for (int off = 32; off > 0; off >>= 1) {
        s  += __shfl_down(s,  off);
        sq += __shfl_down(sq, off);
    }
    const int wave = tid >> 6;
    if ((tid & 63) == 0) { red[wave * 2] = s; red[wave * 2 + 1] = sq; }
    __syncthreads();
    if (tid == 0) {
        const float S = red[0] + red[2] + red[4] + red[6];
        const float Q = red[1] + red[3] + red[5] + red[7];
        const float mean = S * (1.0f / LSEQ);
        const float var  = Q * (1.0f / LSEQ) - mean * mean;
        const float stdv = sqrtf(var + 1e-5f);
        mean_s = mean;
        rstd_s = 1.0f / stdv;
        stats_ws[b * 2]     = mean;
        stats_ws[b * 2 + 1] = stdv;
    }
    __syncthreads();
    const float mean = mean_s, rstd = rstd_s;
    #pragma unroll
    for (int i = 0; i < 4; ++i)
        xn[tid + 256 * i] = (v[i] - mean) * rstd;
    __syncthreads();

    // ---- patch projection: xp[p][h], thread h
    {
        const int h = tid;
        float wrow[16];
        #pragma unroll
        for (int j = 0; j < 16; ++j) wrow[j] = W_proj[h * 16 + j];
        const float bp = b_proj[h];
        #pragma unroll
        for (int p = 0; p < NP; ++p) {
            float acc = bp;
            #pragma unroll
            for (int j = 0; j < 16; ++j) acc += xn[p * 16 + j] * wrow[j];
            xp_s[p * DMODEL + h] = acc;
            xp_ws[((size_t)b * NP + p) * DMODEL + h] = acc;
        }
    }
    __syncthreads();

    // ---- router logits (threads 0..31 -> (p,e))
    if (tid < 32) {
        const int p = tid >> 3, e = tid & 7;
        float acc = b_router[e];
        const float* wr = W_router + e * DMODEL;
        const float* xp = xp_s + p * DMODEL;
        #pragma unroll 8
        for (int h = 0; h < DMODEL; ++h) acc += xp[h] * wr[h];
        lg[tid] = acc;
    }
    __syncthreads();

    // ---- softmax over 8 experts (threads 0..3 -> p)
    if (tid < NP) {
        const int p = tid;
        float m = -1e30f;
        #pragma unroll
        for (int e = 0; e < NEXP; ++e) m = fmaxf(m, lg[p * 8 + e]);
        float ex[NEXP];
        float sum = 0.f;
        #pragma unroll
        for (int e = 0; e < NEXP; ++e) { ex[e] = expf(lg[p * 8 + e] - m); sum += ex[e]; }
        const float inv = 1.0f / sum;
        #pragma unroll
        for (int e = 0; e < NEXP; ++e)
            gates_ws[((size_t)b * NP + p) * NEXP + e] = ex[e] * inv;
    }
}

// ---------------------------------------------------------------------------
// Kernel B: batch-tiled expert matvecs, d-split for occupancy.
// grid = 1024: bid -> (bg2 = bid>>6 [16 pairs], hq = (bid>>4)&3,
//                      dh = (bid>>3)&1, e = bid&7);
// block = 256: tid -> (p = tid>>6, hl = tid&63), h = hq*64+hl.
// Each block reduces HALF the d range (128) -> 4 blocks/CU, 4 waves/SIMD
// (R6/R7: occupancy is the binding constraint, not traffic).
// e in low 3 bits of bid => XCD = bid%8 = e: each XCD's L2 serves one
// expert's Wt slice (256 KB) across all 16 batch-pair blocks.
// Disjoint partial writes (16 buffers) -> deterministic, no atomics.
// Bias folded into the dh=0 partial.
// ---------------------------------------------------------------------------
__global__ __launch_bounds__(256, 4) void k_expert(
    const float* __restrict__ Wt, const float* __restrict__ b_experts,
    const float* __restrict__ xp_ws, const float* __restrict__ gates_ws,
    float* __restrict__ flat_part)
{
    const int bid = blockIdx.x;
    const int bg2 = bid >> 6;           // batch pair 0..15
    const int r   = bid & 63;
    const int hq  = r >> 4;             // 0..3
    const int dh  = (r >> 3) & 1;       // 0..1  (d-half)
    const int e   = r & 7;              // 0..7
    const int b0  = bg2 * 2;
    const int tid = threadIdx.x;
    const int p   = tid >> 6;
    const int hl  = tid & 63;
    const int h   = (hq << 6) + hl;
    const int d0  = dh << 7;            // 0 or 128

    __shared__ float xp_s[2 * NP * DMODEL];   // [i][p][256], 8 KB
    __shared__ float g_s[2 * NP * NEXP];      // [i][p][8]

    // stage xp for both batches (2048 consecutive floats), coalesced float4
    {
        const float4* src = (const float4*)(xp_ws + ((size_t)b0 << 10));
        float4* dst = (float4*)xp_s;
        dst[tid]       = src[tid];
        dst[tid + 256] = src[tid + 256];
    }
    if (tid < 64) g_s[tid] = gates_ws[(size_t)b0 * (NP * NEXP) + tid];
    __syncthreads();

    const float* wt  = Wt + ((size_t)e << 16) + ((size_t)d0 << 8) + h;
    const float4* xpA = (const float4*)(xp_s + (p << 8) + d0);       // batch b0
    const float4* xpB = (const float4*)(xp_s + ((4 + p) << 8) + d0); // batch b0+1

    float a0 = 0.f, a1 = 0.f;
    #pragma unroll 8
    for (int q = 0; q < 32; ++q) {            // 128 d's per block
        const float w0 = wt[(size_t)(4 * q + 0) << 8];
        const float w1 = wt[(size_t)(4 * q + 1) << 8];
        const float w2 = wt[(size_t)(4 * q + 2) << 8];
        const float w3 = wt[(size_t)(4 * q + 3) << 8];
        const float4 xA = xpA[q];
        const float4 xB = xpB[q];
        a0 += w0 * xA.x + w1 * xA.y + w2 * xA.z + w3 * xA.w;
        a1 += w0 * xB.x + w1 * xB.y + w2 * xB.z + w3 * xB.w;
    }

    const float g0 = g_s[(p << 3) + e];
    const float g1 = g_s[32 + (p << 3) + e];
    const float bias = (dh == 0) ? b_experts[(e << 8) + h] : 0.f;
    const int part = (e << 1) | dh;           // 0..15
    flat_part[(((size_t)part * NB + b0)     << 10) + (p << 8) + h] = g0 * (a0 + bias);
    flat_part[(((size_t)part * NB + b0 + 1) << 10) + (p << 8) + h] = g1 * (a1 + bias);
}

// ---------------------------------------------------------------------------
// Kernel C: sum 16 partials, un-normalize, head matvec.
// grid = 256: bid -> (b = bid>>3, kq = bid&7); block = 256 (4 waves).
// Each block handles 12 of the 96 outputs; the 16-partial staging sum is
// redundantly recomputed per kq group (64 KB L2 reads -> cheap), buying
// full-chip occupancy for the latency-bound W_head reads.
// ---------------------------------------------------------------------------
__global__ __launch_bounds__(256) void k_head(
    const float* __restrict__ flat_part, const float* __restrict__ stats_ws,
    const float* __restrict__ W_head, const float* __restrict__ b_head,
    float* __restrict__ out)
{
    const int b   = blockIdx.x >> 3;
    const int kq  = blockIdx.x & 7;
    const int tid = threadIdx.x;
    __shared__ float4 f4s[DMODEL];   // 1024 floats

    const float mean = stats_ws[b * 2];
    const float stdv = stats_ws[b * 2 + 1];

    // stage: f[l] = (sum_part part[i][b][l]) * std + mean   (fixed i-order)
    {
        float4 acc = make_float4(0.f, 0.f, 0.f, 0.f);
        #pragma unroll
        for (int i = 0; i < NPART; ++i) {
            const float4 t = ((const float4*)(flat_part + (((size_t)i * NB + b) << 10)))[tid];
            acc.x += t.x; acc.y += t.y; acc.z += t.z; acc.w += t.w;
        }
        acc.x = acc.x * stdv + mean;
        acc.y = acc.y * stdv + mean;
        acc.z = acc.z * stdv + mean;
        acc.w = acc.w * stdv + mean;
        f4s[tid] = acc;
    }
    __syncthreads();

    const int lane = tid & 63;
    const int w    = tid >> 6;
    float4 fr[4];
    #pragma unroll
    for (int c = 0; c < 4; ++c) fr[c] = f4s[lane + 64 * c];

    #pragma unroll
    for (int i = 0; i < 3; ++i) {
        const int k = kq * 12 + w + 4 * i;
        const float4* wr = (const float4*)(W_head + (size_t)k * LSEQ);
        float a = 0.f;
        #pragma unroll
        for (int c = 0; c < 4; ++c) {
            const float4 t = wr[lane + 64 * c];
            a += t.x * fr[c].x + t.y * fr[c].y + t.z * fr[c].z + t.w * fr[c].w;
        }
        #pragma unroll
        for (int off = 32; off > 0; off >>= 1)
            a += __shfl_xor(a, off);
        if (lane == 0)
            out[(size_t)b * PRED + k] = b_head[k] + a;
    }
}

// ---------------------------------------------------------------------------
extern "C" void kernel_launch(void* const* d_in, const int* in_sizes, int n_in,
                              void* d_out, int out_size, void* d_ws, size_t ws_size,
                              hipStream_t stream)
{
    const float* x         = (const float*)d_in[0];
    const float* W_proj    = (const float*)d_in[4];
    const float* b_proj    = (const float*)d_in[5];
    const float* W_router  = (const float*)d_in[6];
    const float* b_router  = (const float*)d_in[7];
    const float* W_experts = (const float*)d_in[8];
    const float* b_experts = (const float*)d_in[9];
    const float* W_head    = (const float*)d_in[10];
    const float* b_head    = (const float*)d_in[11];
    float* out = (float*)d_out;
    float* ws  = (float*)d_ws;

    float* Wt        = ws;
    float* xp_ws     = ws + WT_FLOATS;
    float* gates_ws  = xp_ws + XP_FLOATS;
    float* stats_ws  = gates_ws + GATES_FLOATS;
    float* flat_part = stats_ws + STATS_FLOATS;   // 16 x NB x LSEQ floats

    k_stats<<<256, 256, 0, stream>>>(x, W_proj, b_proj, W_router, b_router,
                                     W_experts, Wt, xp_ws, gates_ws, stats_ws);
    k_expert<<<1024, 256, 0, stream>>>(Wt, b_experts, xp_ws, gates_ws, flat_part);
    k_head<<<256, 256, 0, stream>>>(flat_part, stats_ws, W_head, b_head, out);
}

// Round 2
// 98.832 us; speedup vs baseline: 1.1200x; 1.0191x over previous
//
#include <hip/hip_runtime.h>
#include <math.h>

// ---------------------------------------------------------------------------
// Problem: B=32, L=1024, C=34, PATCH=16, d=256, E=8, pred=96.
// Algebraic reductions (verified R1-R7):
//   * final [:, :, :1] slice -> only channel n=0 per batch (series x[b,:,2])
//   * flat[:, :1024] truncation -> only patches p=0..3 contribute
// => 32 series, 4 patches each, 8 expert 256x256 matvecs per (b,p), one
//    96x1024 head matvec per b.  ~0.3 GFLOP; structure/latency-bound.
//
// LESSONS: R4 - no hand-rolled cross-workgroup handoff (XCD L2 non-coherent).
//   R5 - uncoalesced per-lane W rows >> launch cost (avoid!).
//   R6/R7 - occupancy beats traffic for the split-kernel expert matvec.
//   R9 - occupancy restructure (1024-block expert, 256-block head): -10us.
//
// R10: collapse 3 kernels -> 2.  Static model says kernel WORK is ~20us;
//   the rest is launch + inter-kernel drain/round-trip structure.
//   k_fused (grid 256 = (b,e), e in low bits -> XCD-local expert slice):
//     redundant per-block stats/xp/router (cheap, coalesced), then 4 d-tiles:
//     coalesced float4 W loads -> LDS transpose (stride 257, conflict-free)
//     -> strided-free matvec, register-prefetch next tile during compute.
//   k_head: sum 8 partials + un-normalize + head matvec (unchanged shape).
//   Eliminates: 1 launch, Wt global transpose, xp/gates round-trips.
// ---------------------------------------------------------------------------

#define NB 32
#define LSEQ 1024
#define CCH 34
#define NP 4
#define DMODEL 256
#define NEXP 8
#define PRED 96
#define DT 64                                   // d-tile width
#define NPART NEXP                              // 8 partial buffers (per e)

#define STATS_FLOATS (NB * 2)                   // 64

// ---------------------------------------------------------------------------
// Kernel A: fused stats + patch-proj + router + expert matvec.
// grid = 256: bid -> (e = bid&7 [XCD-local], b = bid>>3); block = 256.
// LDS: wtT[64][257] transposed W tile (66KB, 2-way banks both directions),
//      xn[1024], xp_s[4][256], small reduce scratch.  ~74 KB -> 1 block/CU.
// ---------------------------------------------------------------------------
__global__ __launch_bounds__(256) void k_fused(
    const float* __restrict__ x,
    const float* __restrict__ W_proj, const float* __restrict__ b_proj,
    const float* __restrict__ W_router, const float* __restrict__ b_router,
    const float* __restrict__ W_experts, const float* __restrict__ b_experts,
    float* __restrict__ flat_part, float* __restrict__ stats_ws)
{
    const int bid = blockIdx.x;
    const int e   = bid & 7;          // low bits -> XCD id -> L2-local slice
    const int b   = bid >> 3;
    const int tid = threadIdx.x;

    __shared__ float wtT[DT][DMODEL + 1];   // transposed tile, 65.8 KB
    __shared__ float xn[LSEQ];
    __shared__ float xp_s[NP * DMODEL];
    __shared__ float red[8];
    __shared__ float lg[32];
    __shared__ float g_s[NP];
    __shared__ float mean_s, rstd_s;

    // ---- issue series loads FIRST (long latency), then tile-0 W loads
    float v[4];
    #pragma unroll
    for (int i = 0; i < 4; ++i)
        v[i] = x[(size_t)(b * LSEQ + tid + 256 * i) * CCH + 2];

    // W tile mapping: c4 = float4 chunk of d (16 per tile), hb+16i = h row.
    // Per wave: 4 rows x 256B contiguous segments -> fully coalesced.
    const int c4 = tid & 15;
    const int hb = tid >> 4;
    const float* wsrc = W_experts + ((size_t)e << 16);
    float4 wreg[16];
    #pragma unroll
    for (int i = 0; i < 16; ++i)
        wreg[i] = *(const float4*)(wsrc + (size_t)(hb + 16 * i) * DMODEL + 4 * c4);

    // ---- stats over the 1024-length series (all 256 threads)
    {
        float s = 0.f, sq = 0.f;
        #pragma unroll
        for (int i = 0; i < 4; ++i) { s += v[i]; sq += v[i] * v[i]; }
        #pragma unroll
        for (int off = 32; off > 0; off >>= 1) {
            s  += __shfl_down(s,  off);
            sq += __shfl_down(sq, off);
        }
        const int wave = tid >> 6;
        if ((tid & 63) == 0) { red[wave * 2] = s; red[wave * 2 + 1] = sq; }
        __syncthreads();
        if (tid == 0) {
            const float S = red[0] + red[2] + red[4] + red[6];
            const float Q = red[1] + red[3] + red[5] + red[7];
            const float mean = S * (1.0f / LSEQ);
            const float var  = Q * (1.0f / LSEQ) - mean * mean;
            const float stdv = sqrtf(var + 1e-5f);
            mean_s = mean;
            rstd_s = 1.0f / stdv;
            if (e == 0) {                 // one writer per batch
                stats_ws[b * 2]     = mean;
                stats_ws[b * 2 + 1] = stdv;
            }
        }
        __syncthreads();
        const float mean = mean_s, rstd = rstd_s;
        #pragma unroll
        for (int i = 0; i < 4; ++i)
            xn[tid + 256 * i] = (v[i] - mean) * rstd;
        __syncthreads();
    }

    // ---- patch projection: xp[p][h], thread h
    {
        const int h = tid;
        float wrow[16];
        #pragma unroll
        for (int j = 0; j < 16; ++j) wrow[j] = W_proj[h * 16 + j];
        const float bp = b_proj[h];
        #pragma unroll
        for (int p = 0; p < NP; ++p) {
            float acc = bp;
            #pragma unroll
            for (int j = 0; j < 16; ++j) acc += xn[p * 16 + j] * wrow[j];
            xp_s[p * DMODEL + h] = acc;
        }
    }
    __syncthreads();

    // ---- router logits, parallel: 8 lanes per (p,e') pair
    {
        const int pe = tid >> 3;          // 0..31 -> (p, e')
        const int sl = tid & 7;
        const int p  = pe >> 3;
        const int er = pe & 7;
        float acc = 0.f;
        #pragma unroll 8
        for (int j = 0; j < 32; ++j) {
            const int hh = sl + 8 * j;
            acc += xp_s[p * DMODEL + hh] * W_router[er * DMODEL + hh];
        }
        acc += __shfl_xor(acc, 4);
        acc += __shfl_xor(acc, 2);
        acc += __shfl_xor(acc, 1);
        if (sl == 0) lg[pe] = acc + b_router[er];
    }
    __syncthreads();

    // ---- softmax over 8 experts; keep only this block's gate g[p]
    if (tid < NP) {
        const int p = tid;
        float m = -1e30f;
        #pragma unroll
        for (int k = 0; k < NEXP; ++k) m = fmaxf(m, lg[p * 8 + k]);
        float ex[NEXP];
        float sum = 0.f;
        #pragma unroll
        for (int k = 0; k < NEXP; ++k) { ex[k] = expf(lg[p * 8 + k] - m); sum += ex[k]; }
        g_s[p] = ex[e] / sum;
    }
    // visibility of g_s covered by the tile-loop barriers below

    // ---- expert matvec: 4 d-tiles, LDS transpose, reg-prefetch next tile
    float acc0 = 0.f, acc1 = 0.f, acc2 = 0.f, acc3 = 0.f;
    for (int t = 0; t < 4; ++t) {
        __syncthreads();   // protect wtT from overwrite while prior reads run
        // transposed store: lane bank = (4*c4 + j + hb) % 32 -> 2-way, free
        #pragma unroll
        for (int i = 0; i < 16; ++i) {
            const int h = hb + 16 * i;
            wtT[4 * c4 + 0][h] = wreg[i].x;
            wtT[4 * c4 + 1][h] = wreg[i].y;
            wtT[4 * c4 + 2][h] = wreg[i].z;
            wtT[4 * c4 + 3][h] = wreg[i].w;
        }
        __syncthreads();
        // prefetch next tile while computing this one
        if (t < 3) {
            #pragma unroll
            for (int i = 0; i < 16; ++i)
                wreg[i] = *(const float4*)(wsrc + (size_t)(hb + 16 * i) * DMODEL
                                           + (t + 1) * DT + 4 * c4);
        }
        // matvec: thread h = tid; wtT read bank = (c + h)%32 -> 2-way, free;
        // xp_s reads are same-address wave broadcasts (free)
        const float* xpp = xp_s + t * DT;
        #pragma unroll 8
        for (int c = 0; c < DT; ++c) {
            const float wv = wtT[c][tid];
            acc0 += xpp[c]       * wv;
            acc1 += xpp[256 + c] * wv;
            acc2 += xpp[512 + c] * wv;
            acc3 += xpp[768 + c] * wv;
        }
    }

    // ---- gated write of this expert's partial (coalesced, disjoint)
    const float bias = b_experts[(e << 8) + tid];
    const size_t base = ((size_t)(e * NB + b) << 10) + tid;
    flat_part[base]         = g_s[0] * (acc0 + bias);
    flat_part[base + 256]   = g_s[1] * (acc1 + bias);
    flat_part[base + 512]   = g_s[2] * (acc2 + bias);
    flat_part[base + 768]   = g_s[3] * (acc3 + bias);
}

// ---------------------------------------------------------------------------
// Kernel B: sum 8 partials, un-normalize, head matvec.
// grid = 256: bid -> (b = bid>>3, kq = bid&7); block = 256 (4 waves).
// ---------------------------------------------------------------------------
__global__ __launch_bounds__(256) void k_head(
    const float* __restrict__ flat_part, const float* __restrict__ stats_ws,
    const float* __restrict__ W_head, const float* __restrict__ b_head,
    float* __restrict__ out)
{
    const int b   = blockIdx.x >> 3;
    const int kq  = blockIdx.x & 7;
    const int tid = threadIdx.x;
    __shared__ float4 f4s[DMODEL];   // 1024 floats

    const float mean = stats_ws[b * 2];
    const float stdv = stats_ws[b * 2 + 1];

    // stage: f[l] = (sum_e part[e][b][l]) * std + mean   (fixed e-order)
    {
        float4 acc = make_float4(0.f, 0.f, 0.f, 0.f);
        #pragma unroll
        for (int i = 0; i < NPART; ++i) {
            const float4 t = ((const float4*)(flat_part + (((size_t)i * NB + b) << 10)))[tid];
            acc.x += t.x; acc.y += t.y; acc.z += t.z; acc.w += t.w;
        }
        acc.x = acc.x * stdv + mean;
        acc.y = acc.y * stdv + mean;
        acc.z = acc.z * stdv + mean;
        acc.w = acc.w * stdv + mean;
        f4s[tid] = acc;
    }
    __syncthreads();

    const int lane = tid & 63;
    const int w    = tid >> 6;
    float4 fr[4];
    #pragma unroll
    for (int c = 0; c < 4; ++c) fr[c] = f4s[lane + 64 * c];

    #pragma unroll
    for (int i = 0; i < 3; ++i) {
        const int k = kq * 12 + w + 4 * i;
        const float4* wr = (const float4*)(W_head + (size_t)k * LSEQ);
        float a = 0.f;
        #pragma unroll
        for (int c = 0; c < 4; ++c) {
            const float4 t = wr[lane + 64 * c];
            a += t.x * fr[c].x + t.y * fr[c].y + t.z * fr[c].z + t.w * fr[c].w;
        }
        #pragma unroll
        for (int off = 32; off > 0; off >>= 1)
            a += __shfl_xor(a, off);
        if (lane == 0)
            out[(size_t)b * PRED + k] = b_head[k] + a;
    }
}

// ---------------------------------------------------------------------------
extern "C" void kernel_launch(void* const* d_in, const int* in_sizes, int n_in,
                              void* d_out, int out_size, void* d_ws, size_t ws_size,
                              hipStream_t stream)
{
    const float* x         = (const float*)d_in[0];
    const float* W_proj    = (const float*)d_in[4];
    const float* b_proj    = (const float*)d_in[5];
    const float* W_router  = (const float*)d_in[6];
    const float* b_router  = (const float*)d_in[7];
    const float* W_experts = (const float*)d_in[8];
    const float* b_experts = (const float*)d_in[9];
    const float* W_head    = (const float*)d_in[10];
    const float* b_head    = (const float*)d_in[11];
    float* out = (float*)d_out;
    float* ws  = (float*)d_ws;

    float* stats_ws  = ws;
    float* flat_part = ws + STATS_FLOATS;   // 8 x NB x LSEQ floats

    k_fused<<<256, 256, 0, stream>>>(x, W_proj, b_proj, W_router, b_router,
                                     W_experts, b_experts, flat_part, stats_ws);
    k_head<<<256, 256, 0, stream>>>(flat_part, stats_ws, W_head, b_head, out);
}